// Round 5
// baseline (340.229 us; speedup 1.0000x reference)
//
#include <hip/hip_runtime.h>

// BilinearResNet fused forward, round 5.
// Round 4 post-mortem: time pinned ~150us across r2-r4 regardless of traffic;
// both pipes idle. Limiter: per-FMA weight broadcast via s_load storms --
// ~1024 scalar loads/chunk/CU through one scalar unit (W_embed >> K$, SGPR
// budget forces batched lgkmcnt stalls). Fix: MFMA is the hardware broadcast.
//   - embed GEMM via mfma_f32_16x16x32_bf16 (x, W cast to bf16 in-flight;
//     logits err ~3.6e-4 << 5.6e-3 threshold).
//   - x staged by global_load_lds (r4-proven, no scratch), XOR source swizzle
//     chosen so A-frag ds_read_b128s are bank-balanced.
//   - W_embed converted once per block to LDS bf16, pitch 808 (balanced
//     B-reads); cols 784..808 zeroed so the K-tail needs no B special case.
//   - bilinear chain + head unchanged (tiny scalar-load count).
// 1024 blocks x 256 thr; LDS 68KB -> 2 blocks/CU.

#define IN_DIM   784
#define D_MODEL  16
#define HIDDEN   6
#define N_BLOCKS 4
#define N_CLS    10
#define BATCH    65536
#define KC       64      // floats per staged chunk
#define NCH      12      // 12*64 = 768, + 16-float tail
#define WPITCH   808     // bf16 pitch for W in LDS

typedef const __attribute__((address_space(1))) void gvoid_t;
typedef __attribute__((address_space(3))) void svoid_t;
typedef __attribute__((ext_vector_type(8))) short bf16x8;
typedef __attribute__((ext_vector_type(4))) float f32x4;

__device__ __forceinline__ short f2bf(float f) {
    unsigned u = __builtin_bit_cast(unsigned, f);
    unsigned r = (u + 0x7FFFu + ((u >> 16) & 1u)) >> 16;
    return (short)r;
}

__global__ __launch_bounds__(256, 2) void bilinear_resnet_fused(
    const float* __restrict__ x,
    const float* __restrict__ W_embed,   // [16][784]
    const float* __restrict__ L_w,       // [4][6][16]
    const float* __restrict__ R_w,       // [4][6][16]
    const float* __restrict__ D_w,       // [4][16][6]
    const float* __restrict__ W_head,    // [10][16]
    float* __restrict__ out)
{
    __shared__ float4 xbuf[2][64 * 16];       // 2 x 16 KB, source-swizzled
    __shared__ short  Wlds[16 * WPITCH];      // 25.9 KB bf16
    __shared__ float4 xtail[64 * 4];          // 4 KB: [64 rows][16 floats]
    __shared__ float  hx[64 * 20];            // 5 KB, pitch 20

    const int tid  = threadIdx.x;
    const int lane = tid & 63;
    const int wv   = __builtin_amdgcn_readfirstlane(tid >> 6);  // 0..3
    const char* xtile = (const char*)(x + (size_t)blockIdx.x * 64 * IN_DIM);

    // ---- W_embed -> bf16 LDS, zero-padded to WPITCH ----
    for (int d = 0; d < D_MODEL; ++d) {
#pragma unroll
        for (int c0 = 0; c0 < WPITCH; c0 += 256) {
            int c = c0 + tid;
            if (c < WPITCH) {
                float v = (c < IN_DIM) ? W_embed[d * IN_DIM + c] : 0.f;
                Wlds[d * WPITCH + c] = f2bf(v);
            }
        }
    }

    // ---- DMA stage of chunk c into xbuf[b]; slot (r,p) holds x[r][p^(r&7)] ----
    auto stage = [&](int c, int b) {
#pragma unroll
        for (int i = 0; i < 4; ++i) {
            const int ii = wv * 4 + i;                 // 0..15, wave-uniform
            const int r  = ii * 4 + (lane >> 4);       // row 0..63
            const int q  = (lane & 15) ^ (r & 7);      // source quad
            const char* src = xtile + (size_t)r * (IN_DIM * 4) + c * (KC * 4) + q * 16;
            char* dst = (char*)&xbuf[b][ii * 64];      // uniform base + lane*16
            __builtin_amdgcn_global_load_lds((gvoid_t*)src, (svoid_t*)dst, 16, 0, 0);
        }
    };
    auto stage_tail = [&]() {
        const int r = wv * 16 + (lane >> 2);
        const int p = lane & 3;
        const char* src = xtile + (size_t)r * (IN_DIM * 4) + 768 * 4 + p * 16;
        char* dst = (char*)&xtail[wv * 64];
        __builtin_amdgcn_global_load_lds((gvoid_t*)src, (svoid_t*)dst, 16, 0, 0);
    };

    stage(0, 0);
    __syncthreads();   // W conversion + chunk 0 DMA complete

    const int m = lane & 15;        // A row-in-tile AND B col (d)
    const int g = lane >> 4;        // k-group
    const int mrow = wv * 16 + m;   // row within 64-row block tile

    f32x4 acc = {0.f, 0.f, 0.f, 0.f};

    for (int c = 0; c < NCH; ++c) {
        if (c + 1 < NCH) stage(c + 1, (c + 1) & 1);
        else             stage_tail();

        const float4* xb = &xbuf[c & 1][0];
#pragma unroll
        for (int ks = 0; ks < 2; ++ks) {
            const int q0 = ks * 8 + 2 * g;             // even
            const int p0 = q0 ^ (m & 7);
            const float4 a0 = xb[mrow * 16 + p0];
            const float4 a1 = xb[mrow * 16 + (p0 ^ 1)];
            bf16x8 af;
            af[0] = f2bf(a0.x); af[1] = f2bf(a0.y);
            af[2] = f2bf(a0.z); af[3] = f2bf(a0.w);
            af[4] = f2bf(a1.x); af[5] = f2bf(a1.y);
            af[6] = f2bf(a1.z); af[7] = f2bf(a1.w);
            const bf16x8 bf = *(const bf16x8*)&Wlds[m * WPITCH + c * KC + ks * 32 + g * 8];
            acc = __builtin_amdgcn_mfma_f32_16x16x32_bf16(af, bf, acc, 0, 0, 0);
        }
        __syncthreads();   // drains vmcnt -> next chunk (or tail) ready
    }

    // ---- K tail: k = 768..784 (16 real + 16 zero) ----
    {
        bf16x8 af;
        if (g < 2) {
            const float4 a0 = xtail[mrow * 4 + g * 2];
            const float4 a1 = xtail[mrow * 4 + g * 2 + 1];
            af[0] = f2bf(a0.x); af[1] = f2bf(a0.y);
            af[2] = f2bf(a0.z); af[3] = f2bf(a0.w);
            af[4] = f2bf(a1.x); af[5] = f2bf(a1.y);
            af[6] = f2bf(a1.z); af[7] = f2bf(a1.w);
        } else {
#pragma unroll
            for (int j = 0; j < 8; ++j) af[j] = 0;
        }
        const bf16x8 bf = *(const bf16x8*)&Wlds[m * WPITCH + 768 + g * 8];  // >=784 zeroed
        acc = __builtin_amdgcn_mfma_f32_16x16x32_bf16(af, bf, acc, 0, 0, 0);
    }

    // ---- C (h_x) -> LDS: row = wv*16 + g*4 + reg, col d = m ----
    {
        const int rbase = wv * 16 + g * 4;
#pragma unroll
        for (int r = 0; r < 4; ++r)
            hx[(rbase + r) * 20 + m] = acc[r];
    }
    __syncthreads();
    if (wv != 0) return;

    // ---- wave 0: one row per lane; bilinear chain + head in fp32 ----
    const int row = blockIdx.x * 64 + lane;
    float hxr[D_MODEL];
    {
        const float4* hp = (const float4*)&hx[lane * 20];
        const float4 t0 = hp[0], t1 = hp[1], t2 = hp[2], t3 = hp[3];
        hxr[0]=t0.x; hxr[1]=t0.y; hxr[2]=t0.z; hxr[3]=t0.w;
        hxr[4]=t1.x; hxr[5]=t1.y; hxr[6]=t1.z; hxr[7]=t1.w;
        hxr[8]=t2.x; hxr[9]=t2.y; hxr[10]=t2.z; hxr[11]=t2.w;
        hxr[12]=t3.x; hxr[13]=t3.y; hxr[14]=t3.z; hxr[15]=t3.w;
    }

#pragma unroll
    for (int b = 0; b < N_BLOCKS; ++b) {
        const float* Lb = L_w + b * HIDDEN * D_MODEL;
        const float* Rb = R_w + b * HIDDEN * D_MODEL;
        const float* Db = D_w + b * D_MODEL * HIDDEN;
        float h[HIDDEN];
#pragma unroll
        for (int j = 0; j < HIDDEN; ++j) {
            float u = 0.f, v = 0.f;
#pragma unroll
            for (int d = 0; d < D_MODEL; ++d) {
                u = fmaf(hxr[d], Lb[j * D_MODEL + d], u);
                v = fmaf(hxr[d], Rb[j * D_MODEL + d], v);
            }
            h[j] = u * v;
        }
#pragma unroll
        for (int d = 0; d < D_MODEL; ++d) {
            float s = hxr[d];
#pragma unroll
            for (int j = 0; j < HIDDEN; ++j) s = fmaf(h[j], Db[d * HIDDEN + j], s);
            hxr[d] = s;
        }
        float* hout = out + (size_t)N_CLS * BATCH + (size_t)b * HIDDEN * BATCH
                      + (size_t)row * HIDDEN;
        const float2 h01 = {h[0], h[1]}, h23 = {h[2], h[3]}, h45 = {h[4], h[5]};
        ((float2*)hout)[0] = h01;
        ((float2*)hout)[1] = h23;
        ((float2*)hout)[2] = h45;
    }

    float* lout = out + (size_t)row * N_CLS;
#pragma unroll
    for (int k = 0; k < N_CLS; k += 2) {
        float s0 = 0.f, s1 = 0.f;
#pragma unroll
        for (int d = 0; d < D_MODEL; ++d) {
            s0 = fmaf(hxr[d], W_head[k * D_MODEL + d], s0);
            s1 = fmaf(hxr[d], W_head[(k + 1) * D_MODEL + d], s1);
        }
        const float2 s = {s0, s1};
        ((float2*)lout)[k >> 1] = s;
    }
}

extern "C" void kernel_launch(void* const* d_in, const int* in_sizes, int n_in,
                              void* d_out, int out_size, void* d_ws, size_t ws_size,
                              hipStream_t stream) {
    const float* x       = (const float*)d_in[0];
    const float* W_embed = (const float*)d_in[1];
    const float* L_w     = (const float*)d_in[2];
    const float* R_w     = (const float*)d_in[3];
    const float* D_w     = (const float*)d_in[4];
    const float* W_head  = (const float*)d_in[5];
    float* out = (float*)d_out;

    const int grid = BATCH / 64;   // 1024 blocks, 64 rows each
    bilinear_resnet_fused<<<grid, 256, 0, stream>>>(
        x, W_embed, L_w, R_w, D_w, W_head, out);
}